// Round 4
// baseline (356.672 us; speedup 1.0000x reference)
//
#include <hip/hip_runtime.h>
#include <stdint.h>

#define Nn 16
#define Cc 128
#define Hh 128
#define Ww 128
#define HWc (Hh*Ww)          // 16384
#define NHW 262144

#define ROWP 17408           // global/LDS row pitch bytes (= 8 groups * 2176)
#define NROW 130             // rows per image incl. top/bottom halo
#define XGRP 2176            // channel-group pitch within a row: 136 pixel slots * 16 B
// row layout: [g=0..7][pixslot p=0..135][16 B], slot p holds image col w = p-1,
// group g holds channels 16g..16g+15. Slots 130..135 are unused pad.

#define PIXB 132             // pack_x LDS transpose tile pitch
#define TPITCH 136           // conv epilogue LDS tile pitch (shorts): breaks 128B bank alias

#define PACKX_BLOCKS (Nn * NROW)   // 2080

typedef int v4i  __attribute__((ext_vector_type(4)));
typedef int v16i __attribute__((ext_vector_type(16)));

typedef __attribute__((address_space(3))) unsigned int lds_uint;
typedef __attribute__((address_space(1))) const unsigned int glob_uint;

__device__ __forceinline__ void gload_lds16(const void* g, void* l) {
    __builtin_amdgcn_global_load_lds((glob_uint*)g, (lds_uint*)l, 16, 0, 0);
}

__device__ __forceinline__ uint32_t sgn8(float v) {
    int8_t s = (v > 0.f) ? 1 : ((v < 0.f) ? -1 : 0);
    return (uint32_t)(uint8_t)s;
}

// ---------------- fused pack: x -> x8 sign layout, w -> A-fragment layout ----
__global__ __launch_bounds__(256) void pack_xw(const float* __restrict__ x,
                                               const float* __restrict__ wt,
                                               char* __restrict__ x8,
                                               char* __restrict__ wswz) {
    int b = blockIdx.x;
    int t = threadIdx.x;

    if (b >= PACKX_BLOCKS) {
        // ---- pack_w part: blocks [2080, 2116) ----
        int gid = (b - PACKX_BLOCKS) * 256 + t;   // 0..9215
        if (gid >= 9216) return;
        int lane = gid & 63, grp = gid >> 6;      // grp 0..143
        int kh = grp & 3, tap = (grp >> 2) % 9, ot = grp / 36;
        int o  = ot * 32 + (lane & 31);
        int cb = kh * 32 + (lane >> 5) * 16;
        uint32_t dw4[4];
        #pragma unroll
        for (int di = 0; di < 4; ++di) {
            uint32_t d = 0;
            #pragma unroll
            for (int j = 0; j < 4; ++j) {
                int c = cb + di * 4 + j;
                float v = wt[((size_t)o * Cc + c) * 9 + tap];
                d |= sgn8(v) << (8 * j);
            }
            dw4[di] = d;
        }
        *(uint4*)(wswz + (size_t)gid * 16) = make_uint4(dw4[0], dw4[1], dw4[2], dw4[3]);
        return;
    }

    // ---- pack_x part ----
    int n = b / NROW, r = b % NROW;
    char* row = x8 + (size_t)b * ROWP;

    if (r == 0 || r == NROW - 1) {        // halo row: zero all
        for (int i = t; i < ROWP / 16; i += 256)
            ((uint4*)row)[i] = make_uint4(0, 0, 0, 0);
        return;
    }
    int h = r - 1;
    // zero left/right halo pixel slots (p=0 and p=129) for all 8 groups
    if (t < 16) {
        int g = t >> 1, p = (t & 1) ? 129 : 0;
        *(uint4*)(row + g * XGRP + p * 16) = make_uint4(0, 0, 0, 0);
    }

    __shared__ __align__(16) char tile[128 * PIXB];   // [w][c] transpose tile
    const float* px = x + (((size_t)n * Cc) * Hh + h) * Ww;   // &x[n][0][h][0]

    // 1024 4x4 transpose tasks: (cg 0..31) x (wq 0..31); lanes sweep wq -> 512B runs
    int wq = t & 31, cgb = t >> 5;
    int w0 = wq * 4;
    #pragma unroll
    for (int s = 0; s < 4; ++s) {
        int c0 = (cgb + 8 * s) * 4;
        float4 v[4];
        #pragma unroll
        for (int j = 0; j < 4; ++j)
            v[j] = *(const float4*)&px[(size_t)(c0 + j) * HWc + w0];
        #pragma unroll
        for (int i = 0; i < 4; ++i) {
            uint32_t d = sgn8(((const float*)&v[0])[i])
                       | (sgn8(((const float*)&v[1])[i]) << 8)
                       | (sgn8(((const float*)&v[2])[i]) << 16)
                       | (sgn8(((const float*)&v[3])[i]) << 24);
            *(uint32_t*)(tile + (w0 + i) * PIXB + c0) = d;
        }
    }
    __syncthreads();
    // write out: 1024 chunks of 16 B; chunk (g, w2) -> row + g*XGRP + (1+w2)*16
    for (int s = 0; s < 4; ++s) {
        int idx = s * 256 + t;
        int w2 = idx & 127, g = idx >> 7;
        const uint32_t* src = (const uint32_t*)(tile + w2 * PIXB + g * 16);
        uint32_t* dst = (uint32_t*)(row + g * XGRP + (1 + w2) * 16);
        dst[0] = src[0]; dst[1] = src[1]; dst[2] = src[2]; dst[3] = src[3];
    }
}

// ---------------- conv: LDS-staged implicit GEMM, mfma_i32_32x32x32_i8 ------
template <typename OutT>
__global__ __launch_bounds__(256) void conv_mfma2(const char* __restrict__ x8,
                                                  const char* __restrict__ wswz,
                                                  OutT* __restrict__ out,
                                                  int2* __restrict__ partials) {
    __shared__ __align__(16) char lds[3 * ROWP];        // 52224 B
    // XCD-aware bijective swizzle: nwg=2048, 8 XCDs, 256 blocks/XCD chunk
    int bid0 = blockIdx.x;
    int bid = (bid0 & 7) * 256 + (bid0 >> 3);
    int n = bid >> 7, h = bid & 127;
    int tid = threadIdx.x, lane = tid & 63, wid = tid >> 6;

    // stage global rows h, h+1, h+2 (= image rows h-1, h, h+1, halo-zeroed)
    const char* gbase = x8 + ((size_t)n * NROW + h) * ROWP;
    for (int task = wid; task < 51; task += 4) {   // 3 rows x 17 KB-chunks
        int rr = task / 17, ck = task % 17;
        gload_lds16(gbase + (size_t)rr * ROWP + ck * 1024 + lane * 16,
                    lds + rr * ROWP + ck * 1024);
    }
    __syncthreads();

    int wy = wid >> 1, wx = wid & 1;
    int ln31 = lane & 31, lq = lane >> 5;

    v16i acc[2][2];
    #pragma unroll
    for (int oi = 0; oi < 2; ++oi)
        #pragma unroll
        for (int pi = 0; pi < 2; ++pi)
            #pragma unroll
            for (int r2 = 0; r2 < 16; ++r2) acc[oi][pi][r2] = 0;

    const char* wb0 = wswz + (size_t)(wy * 2 * 9) * 4096 + lane * 16;
    // pixel/channel fragment base: pixel slot (1 + wx*64 + ln31), channel group lq
    const char* lb  = lds + (size_t)(1 + wx * 64 + ln31) * 16 + lq * XGRP;

    #pragma unroll
    for (int tap = 0; tap < 9; ++tap) {
        int rr = tap / 3, dw = tap % 3 - 1;
        // hoist all 8 weight fragments for this tap (L2-resident)
        v4i a0[4], a1[4];
        #pragma unroll
        for (int kh = 0; kh < 4; ++kh) {
            a0[kh] = *(const v4i*)(wb0 + (tap * 4 + kh) * 1024);
            a1[kh] = *(const v4i*)(wb0 + (36 + tap * 4 + kh) * 1024);
        }
        const char* pb = lb + rr * ROWP + dw * 16;
        #pragma unroll
        for (int kh = 0; kh < 4; ++kh) {
            v4i b0 = *(const v4i*)(pb + kh * (2 * XGRP));
            v4i b1 = *(const v4i*)(pb + kh * (2 * XGRP) + 512);   // pixel +32
            acc[0][0] = __builtin_amdgcn_mfma_i32_32x32x32_i8(a0[kh], b0, acc[0][0], 0, 0, 0);
            acc[0][1] = __builtin_amdgcn_mfma_i32_32x32x32_i8(a0[kh], b1, acc[0][1], 0, 0, 0);
            acc[1][0] = __builtin_amdgcn_mfma_i32_32x32x32_i8(a1[kh], b0, acc[1][0], 0, 0, 0);
            acc[1][1] = __builtin_amdgcn_mfma_i32_32x32x32_i8(a1[kh], b1, acc[1][1], 0, 0, 0);
        }
    }

    OutT* po = out + ((size_t)n * Cc) * HWc + (size_t)h * Ww;

    if constexpr (sizeof(OutT) == 2) {
        // ---- repack through LDS: coalesced uint4 stores + fused stats ----
        __syncthreads();                       // staged input no longer needed
        short* tileS = (short*)lds;            // [128][TPITCH]
        #pragma unroll
        for (int oi = 0; oi < 2; ++oi)
            #pragma unroll
            for (int pi = 0; pi < 2; ++pi) {
                int wcol = wx * 64 + pi * 32 + ln31;
                #pragma unroll
                for (int r2 = 0; r2 < 16; ++r2) {
                    int orow = wy * 64 + oi * 32 + (r2 & 3) + 8 * (r2 >> 2) + 4 * lq;
                    tileS[orow * TPITCH + wcol] = (short)acc[oi][pi][r2];
                }
            }
        __syncthreads();
        // coalesced store: 2048 uint4 chunks (c-row, k)
        for (int idx = tid; idx < 2048; idx += 256) {
            int c = idx >> 4, k = idx & 15;
            *(uint4*)(po + (size_t)c * HWc + k * 8) =
                *(const uint4*)(tileS + c * TPITCH + k * 8);
        }
        // fused per-block channel stats: 2 threads per channel, 64 cols each
        int c = tid >> 1, half = tid & 1;
        const short* rp = tileS + c * TPITCH + half * 64;
        int S = 0, Q = 0;
        #pragma unroll
        for (int k = 0; k < 8; ++k) {          // 8 x int4 = 64 shorts
            int4 vv = *(const int4*)(rp + k * 8);
            int ua[4] = {vv.x, vv.y, vv.z, vv.w};
            #pragma unroll
            for (int j = 0; j < 4; ++j) {
                int s0 = (short)(ua[j] & 0xffff), s1 = (short)(ua[j] >> 16);
                S += s0 + s1;
                Q += s0 * s0 + s1 * s1;
            }
        }
        S += __shfl_xor(S, 1);
        Q += __shfl_xor(Q, 1);
        if (half == 0) partials[(size_t)bid * 128 + c] = make_int2(S, Q);
    } else {
        // float fallback: scattered scalar stores (stats done by statsf)
        #pragma unroll
        for (int oi = 0; oi < 2; ++oi)
            #pragma unroll
            for (int pi = 0; pi < 2; ++pi) {
                int wcol = wx * 64 + pi * 32 + ln31;
                #pragma unroll
                for (int r2 = 0; r2 < 16; ++r2) {
                    int orow = wy * 64 + oi * 32 + (r2 & 3) + 8 * (r2 >> 2) + 4 * lq;
                    po[(size_t)orow * HWc + wcol] = (OutT)acc[oi][pi][r2];
                }
            }
    }
}

// ---------------- stats fallback (float conv) --------------------------------
__global__ __launch_bounds__(256) void statsf(const float* __restrict__ conv,
                                              unsigned long long* __restrict__ stats) {
    int b = blockIdx.x;
    int c = b & 127, n = b >> 7;
    const float4* p = (const float4*)(conv + (size_t)(n * Cc + c) * HWc);
    int sum = 0, sq = 0;
    for (int i = threadIdx.x; i < HWc / 4; i += 256) {
        float4 v = p[i];
        int a = (int)v.x, d = (int)v.y, e = (int)v.z, f = (int)v.w;
        sum += a + d + e + f;
        sq  += a * a + d * d + e * e + f * f;
    }
    #pragma unroll
    for (int off = 32; off > 0; off >>= 1) {
        sum += __shfl_down(sum, off);
        sq  += __shfl_down(sq, off);
    }
    __shared__ int wsum[4], wsq[4];
    int wave = threadIdx.x >> 6, lane = threadIdx.x & 63;
    if (lane == 0) { wsum[wave] = sum; wsq[wave] = sq; }
    __syncthreads();
    if (threadIdx.x == 0) {
        long long S = 0, Q = 0;
        #pragma unroll
        for (int i = 0; i < 4; ++i) { S += wsum[i]; Q += wsq[i]; }
        atomicAdd(&stats[c],       (unsigned long long)S);
        atomicAdd(&stats[128 + c], (unsigned long long)Q);
    }
}

// ---------------- apply16: inline stats reduce + BN + hardtanh + residual ----
__global__ __launch_bounds__(256) void apply16(float* __restrict__ out,
                                               const short* __restrict__ conv,
                                               const float* __restrict__ x,
                                               const int2* __restrict__ partials,
                                               const float* __restrict__ gamma,
                                               const float* __restrict__ beta) {
    int b = blockIdx.x;            // (n, c)
    int c = b & 127, n = b >> 7;
    size_t basei = (size_t)(n * Cc + c) * HWc;

    // inline reduction of channel c over the 2048 conv-block partials (L2-hot)
    long long S = 0, Q = 0;
    for (int i = threadIdx.x; i < Nn * Hh; i += 256) {
        int2 v = partials[(size_t)i * 128 + c];
        S += v.x; Q += v.y;
    }
    #pragma unroll
    for (int off = 32; off > 0; off >>= 1) {
        S += __shfl_down(S, off);
        Q += __shfl_down(Q, off);
    }
    __shared__ long long sS[4], sQ[4];
    __shared__ float sScale, sShift;
    int wave = threadIdx.x >> 6, lane = threadIdx.x & 63;
    if (lane == 0) { sS[wave] = S; sQ[wave] = Q; }
    __syncthreads();
    if (threadIdx.x == 0) {
        long long St = 0, Qt = 0;
        #pragma unroll
        for (int i = 0; i < 4; ++i) { St += sS[i]; Qt += sQ[i]; }
        double m   = (double)St / (double)NHW;
        double var = (double)Qt / (double)NHW - m * m;
        float inv  = (float)(1.0 / sqrt(var + 1e-5));
        float scale = inv * gamma[c];
        sScale = scale;
        sShift = beta[c] - (float)m * scale;
    }
    __syncthreads();
    float scale = sScale, shift = sShift;

    const uint4*  pc = (const uint4*)(conv + basei);   // 8 vals / 16 B
    const float4* px = (const float4*)(x + basei);
    float4*       po = (float4*)(out + basei);
    for (int i = threadIdx.x; i < HWc / 8; i += 256) {
        uint4 v = pc[i];
        uint32_t ua[4] = {v.x, v.y, v.z, v.w};
        #pragma unroll
        for (int half = 0; half < 2; ++half) {
            float4 r = px[i * 2 + half];
            float4 o;
            float c0 = (float)(short)(ua[half * 2]     & 0xffff);
            float c1 = (float)(short)(ua[half * 2]     >> 16);
            float c2 = (float)(short)(ua[half * 2 + 1] & 0xffff);
            float c3 = (float)(short)(ua[half * 2 + 1] >> 16);
            o.x = fminf(fmaxf(c0 * scale + shift, -1.0f), 1.0f) + r.x;
            o.y = fminf(fmaxf(c1 * scale + shift, -1.0f), 1.0f) + r.y;
            o.z = fminf(fmaxf(c2 * scale + shift, -1.0f), 1.0f) + r.z;
            o.w = fminf(fmaxf(c3 * scale + shift, -1.0f), 1.0f) + r.w;
            po[i * 2 + half] = o;
        }
    }
}

__device__ __forceinline__ void bn_coef(const unsigned long long* stats,
                                        const float* gamma, const float* beta,
                                        int c, float& scale, float& shift) {
    long long S = (long long)stats[c];
    long long Q = (long long)stats[128 + c];
    double m   = (double)S / (double)NHW;
    double var = (double)Q / (double)NHW - m * m;
    float inv  = (float)(1.0 / sqrt(var + 1e-5));
    scale = inv * gamma[c];
    shift = beta[c] - (float)m * scale;
}

__global__ __launch_bounds__(256) void applyf(float* __restrict__ out,
                                              const float* __restrict__ x,
                                              const unsigned long long* __restrict__ stats,
                                              const float* __restrict__ gamma,
                                              const float* __restrict__ beta) {
    int b = blockIdx.x;
    int c = b & 127, n = b >> 7;
    size_t basei = (size_t)(n * Cc + c) * HWc;
    float scale, shift;
    bn_coef(stats, gamma, beta, c, scale, shift);

    float4* po = (float4*)(out + basei);
    const float4* px = (const float4*)(x + basei);
    for (int i = threadIdx.x; i < HWc / 4; i += 256) {
        float4 v = po[i];
        float4 r = px[i];
        v.x = fminf(fmaxf(v.x * scale + shift, -1.0f), 1.0f) + r.x;
        v.y = fminf(fmaxf(v.y * scale + shift, -1.0f), 1.0f) + r.y;
        v.z = fminf(fmaxf(v.z * scale + shift, -1.0f), 1.0f) + r.z;
        v.w = fminf(fmaxf(v.w * scale + shift, -1.0f), 1.0f) + r.w;
        po[i] = v;
    }
}

extern "C" void kernel_launch(void* const* d_in, const int* in_sizes, int n_in,
                              void* d_out, int out_size, void* d_ws, size_t ws_size,
                              hipStream_t stream) {
    const float* x     = (const float*)d_in[0];
    const float* wt    = (const float*)d_in[1];
    const float* gamma = (const float*)d_in[2];
    const float* beta  = (const float*)d_in[3];
    float* out = (float*)d_out;

    char* ws = (char*)d_ws;
    unsigned long long* stats = (unsigned long long*)ws;      // 2048 B (fallback only)
    char* wswz = ws + 4096;                                   // 147456 B
    int2* partials = (int2*)(ws + 262144);                    // 2048*128*8 = 2 MB
    char* x8   = ws + 262144 + 2097152;                       // 16*130*17408 = 36208640 B
    const size_t x8_bytes = (size_t)Nn * NROW * ROWP;
    short* conv16 = (short*)(ws + 262144 + 2097152 + x8_bytes);
    const size_t need16 = 262144 + 2097152 + x8_bytes + (size_t)NHW * Cc * 2;

    pack_xw<<<PACKX_BLOCKS + 36, 256, 0, stream>>>(x, wt, x8, wswz);

    if (ws_size >= need16) {
        conv_mfma2<short><<<Nn * Hh, 256, 0, stream>>>(x8, wswz, conv16, partials);
        apply16<<<Nn * Cc, 256, 0, stream>>>(out, conv16, x, partials, gamma, beta);
    } else {
        hipMemsetAsync(stats, 0, 2048, stream);
        conv_mfma2<float><<<Nn * Hh, 256, 0, stream>>>(x8, wswz, out, partials);
        statsf<<<Nn * Cc, 256, 0, stream>>>(out, stats);
        applyf<<<Nn * Cc, 256, 0, stream>>>(out, x, stats, gamma, beta);
    }
}

// Round 5
// 331.143 us; speedup vs baseline: 1.0771x; 1.0771x over previous
//
#include <hip/hip_runtime.h>
#include <stdint.h>

#define Nn 16
#define Cc 128
#define Hh 128
#define Ww 128
#define HWc (Hh*Ww)          // 16384
#define NHW 262144

#define ROWP 17408           // global/LDS row pitch bytes (= 8 groups * 2176)
#define NROW 130             // rows per image incl. top/bottom halo
#define XGRP 2176            // channel-group pitch within a row: 136 pixel slots * 16 B
// row layout: [g=0..7][pixslot p=0..135][16 B], slot p holds image col w = p-1,
// group g holds channels 16g..16g+15. Slots 130..135 are unused pad.

#define PIXB 132             // pack_x LDS transpose tile pitch
#define TPITCH 136           // conv epilogue LDS tile pitch (shorts): breaks 128B bank alias

#define PACKX_BLOCKS (Nn * NROW)   // 2080

typedef int v4i  __attribute__((ext_vector_type(4)));
typedef int v16i __attribute__((ext_vector_type(16)));
typedef float v4f __attribute__((ext_vector_type(4)));
typedef unsigned int v4u __attribute__((ext_vector_type(4)));

typedef __attribute__((address_space(3))) unsigned int lds_uint;
typedef __attribute__((address_space(1))) const unsigned int glob_uint;

__device__ __forceinline__ void gload_lds16(const void* g, void* l) {
    __builtin_amdgcn_global_load_lds((glob_uint*)g, (lds_uint*)l, 16, 0, 0);
}

__device__ __forceinline__ uint32_t sgn8(float v) {
    int8_t s = (v > 0.f) ? 1 : ((v < 0.f) ? -1 : 0);
    return (uint32_t)(uint8_t)s;
}

// ---------------- fused pack: x -> x8 sign layout, w -> A-fragment layout ----
__global__ __launch_bounds__(256) void pack_xw(const float* __restrict__ x,
                                               const float* __restrict__ wt,
                                               char* __restrict__ x8,
                                               char* __restrict__ wswz) {
    int b = blockIdx.x;
    int t = threadIdx.x;

    if (b >= PACKX_BLOCKS) {
        // ---- pack_w part: blocks [2080, 2116) ----
        int gid = (b - PACKX_BLOCKS) * 256 + t;   // 0..9215
        if (gid >= 9216) return;
        int lane = gid & 63, grp = gid >> 6;      // grp 0..143
        int kh = grp & 3, tap = (grp >> 2) % 9, ot = grp / 36;
        int o  = ot * 32 + (lane & 31);
        int cb = kh * 32 + (lane >> 5) * 16;
        uint32_t dw4[4];
        #pragma unroll
        for (int di = 0; di < 4; ++di) {
            uint32_t d = 0;
            #pragma unroll
            for (int j = 0; j < 4; ++j) {
                int c = cb + di * 4 + j;
                float v = wt[((size_t)o * Cc + c) * 9 + tap];
                d |= sgn8(v) << (8 * j);
            }
            dw4[di] = d;
        }
        *(uint4*)(wswz + (size_t)gid * 16) = make_uint4(dw4[0], dw4[1], dw4[2], dw4[3]);
        return;
    }

    // ---- pack_x part ----
    int n = b / NROW, r = b % NROW;
    char* row = x8 + (size_t)b * ROWP;

    if (r == 0 || r == NROW - 1) {        // halo row: zero all
        #pragma unroll
        for (int k = 0; k < 5; ++k) {
            int i = t + k * 256;
            if (i < ROWP / 16) ((uint4*)row)[i] = make_uint4(0, 0, 0, 0);
        }
        return;
    }
    int h = r - 1;
    // zero left/right halo pixel slots (p=0 and p=129) for all 8 groups
    if (t < 16) {
        int g = t >> 1, p = (t & 1) ? 129 : 0;
        *(uint4*)(row + g * XGRP + p * 16) = make_uint4(0, 0, 0, 0);
    }

    __shared__ __align__(16) char tile[128 * PIXB];   // [w][c] transpose tile
    const float* px = x + (((size_t)n * Cc) * Hh + h) * Ww;   // &x[n][0][h][0]

    // 1024 4x4 transpose tasks: (cg 0..31) x (wq 0..31); lanes sweep wq -> 512B runs
    int wq = t & 31, cgb = t >> 5;
    int w0 = wq * 4;
    #pragma unroll
    for (int s = 0; s < 4; ++s) {
        int c0 = (cgb + 8 * s) * 4;
        float4 v[4];
        #pragma unroll
        for (int j = 0; j < 4; ++j)
            v[j] = *(const float4*)&px[(size_t)(c0 + j) * HWc + w0];
        #pragma unroll
        for (int i = 0; i < 4; ++i) {
            uint32_t d = sgn8(((const float*)&v[0])[i])
                       | (sgn8(((const float*)&v[1])[i]) << 8)
                       | (sgn8(((const float*)&v[2])[i]) << 16)
                       | (sgn8(((const float*)&v[3])[i]) << 24);
            *(uint32_t*)(tile + (w0 + i) * PIXB + c0) = d;
        }
    }
    __syncthreads();
    // write out: 1024 chunks of 16 B; chunk (g, w2) -> row + g*XGRP + (1+w2)*16
    #pragma unroll
    for (int s = 0; s < 4; ++s) {
        int idx = s * 256 + t;
        int w2 = idx & 127, g = idx >> 7;
        const uint32_t* src = (const uint32_t*)(tile + w2 * PIXB + g * 16);
        uint32_t* dst = (uint32_t*)(row + g * XGRP + (1 + w2) * 16);
        dst[0] = src[0]; dst[1] = src[1]; dst[2] = src[2]; dst[3] = src[3];
    }
}

// ---------------- conv: LDS-staged implicit GEMM, mfma_i32_32x32x32_i8 ------
template <typename OutT>
__global__ __launch_bounds__(256) void conv_mfma2(const char* __restrict__ x8,
                                                  const char* __restrict__ wswz,
                                                  OutT* __restrict__ out,
                                                  int2* __restrict__ partials) {
    __shared__ __align__(16) char lds[3 * ROWP];        // 52224 B
    // XCD-aware bijective swizzle: nwg=2048, 8 XCDs, 256 blocks/XCD chunk
    int bid0 = blockIdx.x;
    int bid = (bid0 & 7) * 256 + (bid0 >> 3);
    int n = bid >> 7, h = bid & 127;
    int tid = threadIdx.x, lane = tid & 63, wid = tid >> 6;

    // stage global rows h, h+1, h+2 (= image rows h-1, h, h+1, halo-zeroed)
    const char* gbase = x8 + ((size_t)n * NROW + h) * ROWP;
    #pragma unroll
    for (int it = 0; it < 13; ++it) {              // 3 rows x 17 KB-chunks = 51 tasks
        int task = wid + it * 4;
        if (it < 12 || task < 51) {
            int rr = task / 17, ck = task % 17;
            gload_lds16(gbase + (size_t)rr * ROWP + ck * 1024 + lane * 16,
                        lds + rr * ROWP + ck * 1024);
        }
    }
    __syncthreads();

    int wy = wid >> 1, wx = wid & 1;
    int ln31 = lane & 31, lq = lane >> 5;

    v16i acc[2][2];
    #pragma unroll
    for (int oi = 0; oi < 2; ++oi)
        #pragma unroll
        for (int pi = 0; pi < 2; ++pi)
            #pragma unroll
            for (int r2 = 0; r2 < 16; ++r2) acc[oi][pi][r2] = 0;

    const char* wb0 = wswz + (size_t)(wy * 2 * 9) * 4096 + lane * 16;
    // pixel/channel fragment base: pixel slot (1 + wx*64 + ln31), channel group lq
    const char* lb  = lds + (size_t)(1 + wx * 64 + ln31) * 16 + lq * XGRP;

    #pragma unroll
    for (int tap = 0; tap < 9; ++tap) {
        int rr = tap / 3, dw = tap % 3 - 1;
        // hoist all 8 weight fragments for this tap (L2-resident)
        v4i a0[4], a1[4];
        #pragma unroll
        for (int kh = 0; kh < 4; ++kh) {
            a0[kh] = *(const v4i*)(wb0 + (tap * 4 + kh) * 1024);
            a1[kh] = *(const v4i*)(wb0 + (36 + tap * 4 + kh) * 1024);
        }
        const char* pb = lb + rr * ROWP + dw * 16;
        #pragma unroll
        for (int kh = 0; kh < 4; ++kh) {
            v4i b0 = *(const v4i*)(pb + kh * (2 * XGRP));
            v4i b1 = *(const v4i*)(pb + kh * (2 * XGRP) + 512);   // pixel +32
            acc[0][0] = __builtin_amdgcn_mfma_i32_32x32x32_i8(a0[kh], b0, acc[0][0], 0, 0, 0);
            acc[0][1] = __builtin_amdgcn_mfma_i32_32x32x32_i8(a0[kh], b1, acc[0][1], 0, 0, 0);
            acc[1][0] = __builtin_amdgcn_mfma_i32_32x32x32_i8(a1[kh], b0, acc[1][0], 0, 0, 0);
            acc[1][1] = __builtin_amdgcn_mfma_i32_32x32x32_i8(a1[kh], b1, acc[1][1], 0, 0, 0);
        }
    }

    OutT* po = out + ((size_t)n * Cc) * HWc + (size_t)h * Ww;

    if constexpr (sizeof(OutT) == 2) {
        // ---- repack through LDS: coalesced uint4 stores + fused stats ----
        __syncthreads();                       // staged input no longer needed
        short* tileS = (short*)lds;            // [128][TPITCH]
        #pragma unroll
        for (int oi = 0; oi < 2; ++oi)
            #pragma unroll
            for (int pi = 0; pi < 2; ++pi) {
                int wcol = wx * 64 + pi * 32 + ln31;
                #pragma unroll
                for (int r2 = 0; r2 < 16; ++r2) {
                    int orow = wy * 64 + oi * 32 + (r2 & 3) + 8 * (r2 >> 2) + 4 * lq;
                    tileS[orow * TPITCH + wcol] = (short)acc[oi][pi][r2];
                }
            }
        __syncthreads();
        // coalesced store: 2048 uint4 chunks (c-row, k), unrolled for MLP
        #pragma unroll
        for (int k = 0; k < 8; ++k) {
            int idx = tid + k * 256;
            int c = idx >> 4, kk = idx & 15;
            *(uint4*)(po + (size_t)c * HWc + kk * 8) =
                *(const uint4*)(tileS + c * TPITCH + kk * 8);
        }
        // fused per-block channel stats: 2 threads per channel, 64 cols each
        int c = tid >> 1, half = tid & 1;
        const short* rp = tileS + c * TPITCH + half * 64;
        int S = 0, Q = 0;
        #pragma unroll
        for (int k = 0; k < 8; ++k) {          // 8 x int4 = 64 shorts
            int4 vv = *(const int4*)(rp + k * 8);
            int ua[4] = {vv.x, vv.y, vv.z, vv.w};
            #pragma unroll
            for (int j = 0; j < 4; ++j) {
                int s0 = (short)(ua[j] & 0xffff), s1 = (short)(ua[j] >> 16);
                S += s0 + s1;
                Q += s0 * s0 + s1 * s1;
            }
        }
        S += __shfl_xor(S, 1);
        Q += __shfl_xor(Q, 1);
        if (half == 0) partials[(size_t)bid * 128 + c] = make_int2(S, Q);
    } else {
        // float fallback: scattered scalar stores (stats done by statsf)
        #pragma unroll
        for (int oi = 0; oi < 2; ++oi)
            #pragma unroll
            for (int pi = 0; pi < 2; ++pi) {
                int wcol = wx * 64 + pi * 32 + ln31;
                #pragma unroll
                for (int r2 = 0; r2 < 16; ++r2) {
                    int orow = wy * 64 + oi * 32 + (r2 & 3) + 8 * (r2 >> 2) + 4 * lq;
                    po[(size_t)orow * HWc + wcol] = (OutT)acc[oi][pi][r2];
                }
            }
    }
}

// ---------------- reduce partials -> per-channel {scale, shift} --------------
__global__ __launch_bounds__(256) void reduce_coef(const int2* __restrict__ partials,
                                                   const float* __restrict__ gamma,
                                                   const float* __restrict__ beta,
                                                   float2* __restrict__ coef) {
    int c = blockIdx.x;            // channel
    long long S = 0, Q = 0;
    #pragma unroll
    for (int k = 0; k < 8; ++k) {
        int i = threadIdx.x + k * 256;
        int2 v = partials[(size_t)i * 128 + c];
        S += v.x; Q += v.y;
    }
    #pragma unroll
    for (int off = 32; off > 0; off >>= 1) {
        S += __shfl_down(S, off);
        Q += __shfl_down(Q, off);
    }
    __shared__ long long sS[4], sQ[4];
    int wave = threadIdx.x >> 6, lane = threadIdx.x & 63;
    if (lane == 0) { sS[wave] = S; sQ[wave] = Q; }
    __syncthreads();
    if (threadIdx.x == 0) {
        long long St = 0, Qt = 0;
        #pragma unroll
        for (int i = 0; i < 4; ++i) { St += sS[i]; Qt += sQ[i]; }
        double m   = (double)St / (double)NHW;
        double var = (double)Qt / (double)NHW - m * m;
        float inv  = (float)(1.0 / sqrt(var + 1e-5));
        float scale = inv * gamma[c];
        coef[c] = make_float2(scale, beta[c] - (float)m * scale);
    }
}

// ---------------- apply16: pure stream, BN + hardtanh + residual -------------
__global__ __launch_bounds__(256) void apply16(float* __restrict__ out,
                                               const short* __restrict__ conv,
                                               const float* __restrict__ x,
                                               const float2* __restrict__ coef,
                                               const float* __restrict__ gamma,
                                               const float* __restrict__ beta) {
    int b = blockIdx.x;            // (n, c)
    int c = b & 127, n = b >> 7;
    size_t basei = (size_t)(n * Cc + c) * HWc;
    float2 sc = coef[c];
    float scale = sc.x, shift = sc.y;

    const v4u* pc = (const v4u*)(conv + basei);   // 8 vals / 16 B
    const v4f* px = (const v4f*)(x + basei);
    v4f*       po = (v4f*)(out + basei);
    int t = threadIdx.x;
    #pragma unroll
    for (int k = 0; k < 8; ++k) {                 // 8 independent iterations -> MLP
        int i = t + k * 256;
        v4u v = pc[i];                            // conv16: normal load (L3-hot)
        v4f r0 = __builtin_nontemporal_load(px + 2 * i);
        v4f r1 = __builtin_nontemporal_load(px + 2 * i + 1);
        float c0 = (float)(short)(v.x & 0xffff), c1 = (float)(short)(v.x >> 16);
        float c2 = (float)(short)(v.y & 0xffff), c3 = (float)(short)(v.y >> 16);
        float c4 = (float)(short)(v.z & 0xffff), c5 = (float)(short)(v.z >> 16);
        float c6 = (float)(short)(v.w & 0xffff), c7 = (float)(short)(v.w >> 16);
        v4f o0, o1;
        o0.x = fminf(fmaxf(c0 * scale + shift, -1.0f), 1.0f) + r0.x;
        o0.y = fminf(fmaxf(c1 * scale + shift, -1.0f), 1.0f) + r0.y;
        o0.z = fminf(fmaxf(c2 * scale + shift, -1.0f), 1.0f) + r0.z;
        o0.w = fminf(fmaxf(c3 * scale + shift, -1.0f), 1.0f) + r0.w;
        o1.x = fminf(fmaxf(c4 * scale + shift, -1.0f), 1.0f) + r1.x;
        o1.y = fminf(fmaxf(c5 * scale + shift, -1.0f), 1.0f) + r1.y;
        o1.z = fminf(fmaxf(c6 * scale + shift, -1.0f), 1.0f) + r1.z;
        o1.w = fminf(fmaxf(c7 * scale + shift, -1.0f), 1.0f) + r1.w;
        __builtin_nontemporal_store(o0, po + 2 * i);
        __builtin_nontemporal_store(o1, po + 2 * i + 1);
    }
}

// ---------------- float fallback path ----------------------------------------
__global__ __launch_bounds__(256) void statsf(const float* __restrict__ conv,
                                              unsigned long long* __restrict__ stats) {
    int b = blockIdx.x;
    int c = b & 127, n = b >> 7;
    const float4* p = (const float4*)(conv + (size_t)(n * Cc + c) * HWc);
    int sum = 0, sq = 0;
    for (int i = threadIdx.x; i < HWc / 4; i += 256) {
        float4 v = p[i];
        int a = (int)v.x, d = (int)v.y, e = (int)v.z, f = (int)v.w;
        sum += a + d + e + f;
        sq  += a * a + d * d + e * e + f * f;
    }
    #pragma unroll
    for (int off = 32; off > 0; off >>= 1) {
        sum += __shfl_down(sum, off);
        sq  += __shfl_down(sq, off);
    }
    __shared__ int wsum[4], wsq[4];
    int wave = threadIdx.x >> 6, lane = threadIdx.x & 63;
    if (lane == 0) { wsum[wave] = sum; wsq[wave] = sq; }
    __syncthreads();
    if (threadIdx.x == 0) {
        long long S = 0, Q = 0;
        #pragma unroll
        for (int i = 0; i < 4; ++i) { S += wsum[i]; Q += wsq[i]; }
        atomicAdd(&stats[c],       (unsigned long long)S);
        atomicAdd(&stats[128 + c], (unsigned long long)Q);
    }
}

__device__ __forceinline__ void bn_coef(const unsigned long long* stats,
                                        const float* gamma, const float* beta,
                                        int c, float& scale, float& shift) {
    long long S = (long long)stats[c];
    long long Q = (long long)stats[128 + c];
    double m   = (double)S / (double)NHW;
    double var = (double)Q / (double)NHW - m * m;
    float inv  = (float)(1.0 / sqrt(var + 1e-5));
    scale = inv * gamma[c];
    shift = beta[c] - (float)m * scale;
}

__global__ __launch_bounds__(256) void applyf(float* __restrict__ out,
                                              const float* __restrict__ x,
                                              const unsigned long long* __restrict__ stats,
                                              const float* __restrict__ gamma,
                                              const float* __restrict__ beta) {
    int b = blockIdx.x;
    int c = b & 127, n = b >> 7;
    size_t basei = (size_t)(n * Cc + c) * HWc;
    float scale, shift;
    bn_coef(stats, gamma, beta, c, scale, shift);

    float4* po = (float4*)(out + basei);
    const float4* px = (const float4*)(x + basei);
    for (int i = threadIdx.x; i < HWc / 4; i += 256) {
        float4 v = po[i];
        float4 r = px[i];
        v.x = fminf(fmaxf(v.x * scale + shift, -1.0f), 1.0f) + r.x;
        v.y = fminf(fmaxf(v.y * scale + shift, -1.0f), 1.0f) + r.y;
        v.z = fminf(fmaxf(v.z * scale + shift, -1.0f), 1.0f) + r.z;
        v.w = fminf(fmaxf(v.w * scale + shift, -1.0f), 1.0f) + r.w;
        po[i] = v;
    }
}

extern "C" void kernel_launch(void* const* d_in, const int* in_sizes, int n_in,
                              void* d_out, int out_size, void* d_ws, size_t ws_size,
                              hipStream_t stream) {
    const float* x     = (const float*)d_in[0];
    const float* wt    = (const float*)d_in[1];
    const float* gamma = (const float*)d_in[2];
    const float* beta  = (const float*)d_in[3];
    float* out = (float*)d_out;

    char* ws = (char*)d_ws;
    unsigned long long* stats = (unsigned long long*)ws;      // 2048 B (fallback only)
    float2* coef = (float2*)(ws + 2048);                      // 1024 B
    char* wswz = ws + 4096;                                   // 147456 B
    int2* partials = (int2*)(ws + 262144);                    // 2048*128*8 = 2 MB
    char* x8   = ws + 262144 + 2097152;                       // 16*130*17408 = 36208640 B
    const size_t x8_bytes = (size_t)Nn * NROW * ROWP;
    short* conv16 = (short*)(ws + 262144 + 2097152 + x8_bytes);
    const size_t need16 = 262144 + 2097152 + x8_bytes + (size_t)NHW * Cc * 2;

    pack_xw<<<PACKX_BLOCKS + 36, 256, 0, stream>>>(x, wt, x8, wswz);

    if (ws_size >= need16) {
        conv_mfma2<short><<<Nn * Hh, 256, 0, stream>>>(x8, wswz, conv16, partials);
        reduce_coef<<<Cc, 256, 0, stream>>>(partials, gamma, beta, coef);
        apply16<<<Nn * Cc, 256, 0, stream>>>(out, conv16, x, coef, gamma, beta);
    } else {
        hipMemsetAsync(stats, 0, 2048, stream);
        conv_mfma2<float><<<Nn * Hh, 256, 0, stream>>>(x8, wswz, out, partials);
        statsf<<<Nn * Cc, 256, 0, stream>>>(out, stats);
        applyf<<<Nn * Cc, 256, 0, stream>>>(out, x, stats, gamma, beta);
    }
}

// Round 6
// 328.681 us; speedup vs baseline: 1.0852x; 1.0075x over previous
//
#include <hip/hip_runtime.h>
#include <stdint.h>

#define Nn 16
#define Cc 128
#define Hh 128
#define Ww 128
#define HWc (Hh*Ww)          // 16384
#define NHW 262144

#define ROWP 17408           // global/LDS row pitch bytes (= 8 groups * 2176)
#define NROW 130             // rows per image incl. top/bottom halo
#define XGRP 2176            // channel-group pitch within a row: 136 pixel slots * 16 B
// row layout: [g=0..7][pixslot p=0..135][16 B], slot p holds image col w = p-1,
// group g holds channels 16g..16g+15. Slots 130..135 are unused pad.

#define PIXB 144             // pack_x LDS transpose tile pitch (16-aligned, 2-way banks)
#define TPITCH 136           // conv epilogue LDS tile pitch (shorts): breaks 128B bank alias

#define PACKX_BLOCKS (Nn * NROW)   // 2080

typedef int v4i  __attribute__((ext_vector_type(4)));
typedef int v16i __attribute__((ext_vector_type(16)));
typedef float v4f __attribute__((ext_vector_type(4)));
typedef unsigned int v4u __attribute__((ext_vector_type(4)));

typedef __attribute__((address_space(3))) unsigned int lds_uint;
typedef __attribute__((address_space(1))) const unsigned int glob_uint;

__device__ __forceinline__ void gload_lds16(const void* g, void* l) {
    __builtin_amdgcn_global_load_lds((glob_uint*)g, (lds_uint*)l, 16, 0, 0);
}

__device__ __forceinline__ uint32_t sgn8(float v) {
    int8_t s = (v > 0.f) ? 1 : ((v < 0.f) ? -1 : 0);
    return (uint32_t)(uint8_t)s;
}

// ---------------- fused pack: x -> x8 sign layout, w -> A-fragment layout ----
__global__ __launch_bounds__(256) void pack_xw(const float* __restrict__ x,
                                               const float* __restrict__ wt,
                                               char* __restrict__ x8,
                                               char* __restrict__ wswz) {
    int b = blockIdx.x;
    int t = threadIdx.x;

    if (b >= PACKX_BLOCKS) {
        // ---- pack_w part: blocks [2080, 2116) ----
        int gid = (b - PACKX_BLOCKS) * 256 + t;   // 0..9215
        if (gid >= 9216) return;
        int lane = gid & 63, grp = gid >> 6;      // grp 0..143
        int kh = grp & 3, tap = (grp >> 2) % 9, ot = grp / 36;
        int o  = ot * 32 + (lane & 31);
        int cb = kh * 32 + (lane >> 5) * 16;
        uint32_t dw4[4];
        #pragma unroll
        for (int di = 0; di < 4; ++di) {
            uint32_t d = 0;
            #pragma unroll
            for (int j = 0; j < 4; ++j) {
                int c = cb + di * 4 + j;
                float v = wt[((size_t)o * Cc + c) * 9 + tap];
                d |= sgn8(v) << (8 * j);
            }
            dw4[di] = d;
        }
        *(uint4*)(wswz + (size_t)gid * 16) = make_uint4(dw4[0], dw4[1], dw4[2], dw4[3]);
        return;
    }

    // ---- pack_x part ----
    int n = b / NROW, r = b % NROW;
    char* row = x8 + (size_t)b * ROWP;

    if (r == 0 || r == NROW - 1) {        // halo row: zero all
        #pragma unroll
        for (int k = 0; k < 5; ++k) {
            int i = t + k * 256;
            if (i < ROWP / 16) ((uint4*)row)[i] = make_uint4(0, 0, 0, 0);
        }
        return;
    }
    int h = r - 1;
    // zero left/right halo pixel slots (p=0 and p=129) for all 8 groups
    if (t < 16) {
        int g = t >> 1, p = (t & 1) ? 129 : 0;
        *(uint4*)(row + g * XGRP + p * 16) = make_uint4(0, 0, 0, 0);
    }

    __shared__ __align__(16) char tile[128 * PIXB];   // [w][c] transpose tile
    const float* px = x + (((size_t)n * Cc) * Hh + h) * Ww;   // &x[n][0][h][0]

    // 1024 4x4 transpose tasks: (cg 0..31) x (wq 0..31); lanes sweep wq -> 512B runs
    int wq = t & 31, cgb = t >> 5;
    int w0 = wq * 4;
    #pragma unroll
    for (int s = 0; s < 4; ++s) {
        int c0 = (cgb + 8 * s) * 4;
        float4 v[4];
        #pragma unroll
        for (int j = 0; j < 4; ++j)
            v[j] = *(const float4*)&px[(size_t)(c0 + j) * HWc + w0];
        #pragma unroll
        for (int i = 0; i < 4; ++i) {
            uint32_t d = sgn8(((const float*)&v[0])[i])
                       | (sgn8(((const float*)&v[1])[i]) << 8)
                       | (sgn8(((const float*)&v[2])[i]) << 16)
                       | (sgn8(((const float*)&v[3])[i]) << 24);
            *(uint32_t*)(tile + (w0 + i) * PIXB + c0) = d;
        }
    }
    __syncthreads();
    // write out: 1024 chunks of 16 B; chunk (g, w2) -> row + g*XGRP + (1+w2)*16
    // PIXB=144 keeps src 16B-aligned -> ds_read_b128 + one dwordx4 store
    #pragma unroll
    for (int s = 0; s < 4; ++s) {
        int idx = s * 256 + t;
        int w2 = idx & 127, g = idx >> 7;
        uint4 chunk = *(const uint4*)(tile + w2 * PIXB + g * 16);
        *(uint4*)(row + g * XGRP + (1 + w2) * 16) = chunk;
    }
}

// ---------------- conv: LDS-staged implicit GEMM, mfma_i32_32x32x32_i8 ------
// __launch_bounds__(256,3): request 3 waves/SIMD (= 3 blocks/CU, matching the
// LDS cap of 3x52224=157KB) so the register allocator keeps VGPR <= ~168.
template <typename OutT>
__global__ __launch_bounds__(256, 3) void conv_mfma2(const char* __restrict__ x8,
                                                  const char* __restrict__ wswz,
                                                  OutT* __restrict__ out,
                                                  int2* __restrict__ partials) {
    __shared__ __align__(16) char lds[3 * ROWP];        // 52224 B
    // XCD-aware bijective swizzle: nwg=2048, 8 XCDs, 256 blocks/XCD chunk
    int bid0 = blockIdx.x;
    int bid = (bid0 & 7) * 256 + (bid0 >> 3);
    int n = bid >> 7, h = bid & 127;
    int tid = threadIdx.x, lane = tid & 63, wid = tid >> 6;

    // stage global rows h, h+1, h+2 (= image rows h-1, h, h+1, halo-zeroed)
    const char* gbase = x8 + ((size_t)n * NROW + h) * ROWP;
    #pragma unroll
    for (int it = 0; it < 13; ++it) {              // 3 rows x 17 KB-chunks = 51 tasks
        int task = wid + it * 4;
        if (it < 12 || task < 51) {
            int rr = task / 17, ck = task % 17;
            gload_lds16(gbase + (size_t)rr * ROWP + ck * 1024 + lane * 16,
                        lds + rr * ROWP + ck * 1024);
        }
    }
    __syncthreads();

    int wy = wid >> 1, wx = wid & 1;
    int ln31 = lane & 31, lq = lane >> 5;

    v16i acc[2][2];
    #pragma unroll
    for (int oi = 0; oi < 2; ++oi)
        #pragma unroll
        for (int pi = 0; pi < 2; ++pi)
            #pragma unroll
            for (int r2 = 0; r2 < 16; ++r2) acc[oi][pi][r2] = 0;

    const char* wb0 = wswz + (size_t)(wy * 2 * 9) * 4096 + lane * 16;
    // pixel/channel fragment base: pixel slot (1 + wx*64 + ln31), channel group lq
    const char* lb  = lds + (size_t)(1 + wx * 64 + ln31) * 16 + lq * XGRP;

    #pragma unroll
    for (int tap = 0; tap < 9; ++tap) {
        int rr = tap / 3, dw = tap % 3 - 1;
        // hoist all 8 weight fragments for this tap (L2-resident)
        v4i a0[4], a1[4];
        #pragma unroll
        for (int kh = 0; kh < 4; ++kh) {
            a0[kh] = *(const v4i*)(wb0 + (tap * 4 + kh) * 1024);
            a1[kh] = *(const v4i*)(wb0 + (36 + tap * 4 + kh) * 1024);
        }
        const char* pb = lb + rr * ROWP + dw * 16;
        #pragma unroll
        for (int kh = 0; kh < 4; ++kh) {
            v4i b0 = *(const v4i*)(pb + kh * (2 * XGRP));
            v4i b1 = *(const v4i*)(pb + kh * (2 * XGRP) + 512);   // pixel +32
            acc[0][0] = __builtin_amdgcn_mfma_i32_32x32x32_i8(a0[kh], b0, acc[0][0], 0, 0, 0);
            acc[0][1] = __builtin_amdgcn_mfma_i32_32x32x32_i8(a0[kh], b1, acc[0][1], 0, 0, 0);
            acc[1][0] = __builtin_amdgcn_mfma_i32_32x32x32_i8(a1[kh], b0, acc[1][0], 0, 0, 0);
            acc[1][1] = __builtin_amdgcn_mfma_i32_32x32x32_i8(a1[kh], b1, acc[1][1], 0, 0, 0);
        }
    }

    OutT* po = out + ((size_t)n * Cc) * HWc + (size_t)h * Ww;

    if constexpr (sizeof(OutT) == 2) {
        // ---- repack through LDS: coalesced uint4 stores + fused stats ----
        __syncthreads();                       // staged input no longer needed
        short* tileS = (short*)lds;            // [128][TPITCH]
        #pragma unroll
        for (int oi = 0; oi < 2; ++oi)
            #pragma unroll
            for (int pi = 0; pi < 2; ++pi) {
                int wcol = wx * 64 + pi * 32 + ln31;
                #pragma unroll
                for (int r2 = 0; r2 < 16; ++r2) {
                    int orow = wy * 64 + oi * 32 + (r2 & 3) + 8 * (r2 >> 2) + 4 * lq;
                    tileS[orow * TPITCH + wcol] = (short)acc[oi][pi][r2];
                }
            }
        __syncthreads();
        // coalesced store: 2048 uint4 chunks (c-row, k), unrolled for MLP
        #pragma unroll
        for (int k = 0; k < 8; ++k) {
            int idx = tid + k * 256;
            int c = idx >> 4, kk = idx & 15;
            *(uint4*)(po + (size_t)c * HWc + kk * 8) =
                *(const uint4*)(tileS + c * TPITCH + kk * 8);
        }
        // fused per-block channel stats: 2 threads per channel, 64 cols each
        int c = tid >> 1, half = tid & 1;
        const short* rp = tileS + c * TPITCH + half * 64;
        int S = 0, Q = 0;
        #pragma unroll
        for (int k = 0; k < 8; ++k) {          // 8 x int4 = 64 shorts
            int4 vv = *(const int4*)(rp + k * 8);
            int ua[4] = {vv.x, vv.y, vv.z, vv.w};
            #pragma unroll
            for (int j = 0; j < 4; ++j) {
                int s0 = (short)(ua[j] & 0xffff), s1 = (short)(ua[j] >> 16);
                S += s0 + s1;
                Q += s0 * s0 + s1 * s1;
            }
        }
        S += __shfl_xor(S, 1);
        Q += __shfl_xor(Q, 1);
        if (half == 0) partials[(size_t)bid * 128 + c] = make_int2(S, Q);
    } else {
        // float fallback: scattered scalar stores (stats done by statsf)
        #pragma unroll
        for (int oi = 0; oi < 2; ++oi)
            #pragma unroll
            for (int pi = 0; pi < 2; ++pi) {
                int wcol = wx * 64 + pi * 32 + ln31;
                #pragma unroll
                for (int r2 = 0; r2 < 16; ++r2) {
                    int orow = wy * 64 + oi * 32 + (r2 & 3) + 8 * (r2 >> 2) + 4 * lq;
                    po[(size_t)orow * HWc + wcol] = (OutT)acc[oi][pi][r2];
                }
            }
    }
}

// ---------------- reduce partials -> per-channel {scale, shift} --------------
__global__ __launch_bounds__(256) void reduce_coef(const int2* __restrict__ partials,
                                                   const float* __restrict__ gamma,
                                                   const float* __restrict__ beta,
                                                   float2* __restrict__ coef) {
    int c = blockIdx.x;            // channel
    long long S = 0, Q = 0;
    #pragma unroll
    for (int k = 0; k < 8; ++k) {
        int i = threadIdx.x + k * 256;
        int2 v = partials[(size_t)i * 128 + c];
        S += v.x; Q += v.y;
    }
    #pragma unroll
    for (int off = 32; off > 0; off >>= 1) {
        S += __shfl_down(S, off);
        Q += __shfl_down(Q, off);
    }
    __shared__ long long sS[4], sQ[4];
    int wave = threadIdx.x >> 6, lane = threadIdx.x & 63;
    if (lane == 0) { sS[wave] = S; sQ[wave] = Q; }
    __syncthreads();
    if (threadIdx.x == 0) {
        long long St = 0, Qt = 0;
        #pragma unroll
        for (int i = 0; i < 4; ++i) { St += sS[i]; Qt += sQ[i]; }
        double m   = (double)St / (double)NHW;
        double var = (double)Qt / (double)NHW - m * m;
        float inv  = (float)(1.0 / sqrt(var + 1e-5));
        float scale = inv * gamma[c];
        coef[c] = make_float2(scale, beta[c] - (float)m * scale);
    }
}

// ---------------- apply16: pure stream, BN + hardtanh + residual -------------
__global__ __launch_bounds__(256) void apply16(float* __restrict__ out,
                                               const short* __restrict__ conv,
                                               const float* __restrict__ x,
                                               const float2* __restrict__ coef,
                                               const float* __restrict__ gamma,
                                               const float* __restrict__ beta) {
    int b = blockIdx.x;            // (n, c)
    int c = b & 127, n = b >> 7;
    size_t basei = (size_t)(n * Cc + c) * HWc;
    float2 sc = coef[c];
    float scale = sc.x, shift = sc.y;

    const v4u* pc = (const v4u*)(conv + basei);   // 8 vals / 16 B
    const v4f* px = (const v4f*)(x + basei);
    v4f*       po = (v4f*)(out + basei);
    int t = threadIdx.x;
    #pragma unroll
    for (int k = 0; k < 8; ++k) {                 // 8 independent iterations -> MLP
        int i = t + k * 256;
        v4u v = pc[i];                            // conv16: normal load (L3-hot)
        v4f r0 = __builtin_nontemporal_load(px + 2 * i);
        v4f r1 = __builtin_nontemporal_load(px + 2 * i + 1);
        float c0 = (float)(short)(v.x & 0xffff), c1 = (float)(short)(v.x >> 16);
        float c2 = (float)(short)(v.y & 0xffff), c3 = (float)(short)(v.y >> 16);
        float c4 = (float)(short)(v.z & 0xffff), c5 = (float)(short)(v.z >> 16);
        float c6 = (float)(short)(v.w & 0xffff), c7 = (float)(short)(v.w >> 16);
        v4f o0, o1;
        o0.x = fminf(fmaxf(c0 * scale + shift, -1.0f), 1.0f) + r0.x;
        o0.y = fminf(fmaxf(c1 * scale + shift, -1.0f), 1.0f) + r0.y;
        o0.z = fminf(fmaxf(c2 * scale + shift, -1.0f), 1.0f) + r0.z;
        o0.w = fminf(fmaxf(c3 * scale + shift, -1.0f), 1.0f) + r0.w;
        o1.x = fminf(fmaxf(c4 * scale + shift, -1.0f), 1.0f) + r1.x;
        o1.y = fminf(fmaxf(c5 * scale + shift, -1.0f), 1.0f) + r1.y;
        o1.z = fminf(fmaxf(c6 * scale + shift, -1.0f), 1.0f) + r1.z;
        o1.w = fminf(fmaxf(c7 * scale + shift, -1.0f), 1.0f) + r1.w;
        __builtin_nontemporal_store(o0, po + 2 * i);
        __builtin_nontemporal_store(o1, po + 2 * i + 1);
    }
}

// ---------------- float fallback path ----------------------------------------
__global__ __launch_bounds__(256) void statsf(const float* __restrict__ conv,
                                              unsigned long long* __restrict__ stats) {
    int b = blockIdx.x;
    int c = b & 127, n = b >> 7;
    const float4* p = (const float4*)(conv + (size_t)(n * Cc + c) * HWc);
    int sum = 0, sq = 0;
    for (int i = threadIdx.x; i < HWc / 4; i += 256) {
        float4 v = p[i];
        int a = (int)v.x, d = (int)v.y, e = (int)v.z, f = (int)v.w;
        sum += a + d + e + f;
        sq  += a * a + d * d + e * e + f * f;
    }
    #pragma unroll
    for (int off = 32; off > 0; off >>= 1) {
        sum += __shfl_down(sum, off);
        sq  += __shfl_down(sq, off);
    }
    __shared__ int wsum[4], wsq[4];
    int wave = threadIdx.x >> 6, lane = threadIdx.x & 63;
    if (lane == 0) { wsum[wave] = sum; wsq[wave] = sq; }
    __syncthreads();
    if (threadIdx.x == 0) {
        long long S = 0, Q = 0;
        #pragma unroll
        for (int i = 0; i < 4; ++i) { S += wsum[i]; Q += wsq[i]; }
        atomicAdd(&stats[c],       (unsigned long long)S);
        atomicAdd(&stats[128 + c], (unsigned long long)Q);
    }
}

__device__ __forceinline__ void bn_coef(const unsigned long long* stats,
                                        const float* gamma, const float* beta,
                                        int c, float& scale, float& shift) {
    long long S = (long long)stats[c];
    long long Q = (long long)stats[128 + c];
    double m   = (double)S / (double)NHW;
    double var = (double)Q / (double)NHW - m * m;
    float inv  = (float)(1.0 / sqrt(var + 1e-5));
    scale = inv * gamma[c];
    shift = beta[c] - (float)m * scale;
}

__global__ __launch_bounds__(256) void applyf(float* __restrict__ out,
                                              const float* __restrict__ x,
                                              const unsigned long long* __restrict__ stats,
                                              const float* __restrict__ gamma,
                                              const float* __restrict__ beta) {
    int b = blockIdx.x;
    int c = b & 127, n = b >> 7;
    size_t basei = (size_t)(n * Cc + c) * HWc;
    float scale, shift;
    bn_coef(stats, gamma, beta, c, scale, shift);

    float4* po = (float4*)(out + basei);
    const float4* px = (const float4*)(x + basei);
    for (int i = threadIdx.x; i < HWc / 4; i += 256) {
        float4 v = po[i];
        float4 r = px[i];
        v.x = fminf(fmaxf(v.x * scale + shift, -1.0f), 1.0f) + r.x;
        v.y = fminf(fmaxf(v.y * scale + shift, -1.0f), 1.0f) + r.y;
        v.z = fminf(fmaxf(v.z * scale + shift, -1.0f), 1.0f) + r.z;
        v.w = fminf(fmaxf(v.w * scale + shift, -1.0f), 1.0f) + r.w;
        po[i] = v;
    }
}

extern "C" void kernel_launch(void* const* d_in, const int* in_sizes, int n_in,
                              void* d_out, int out_size, void* d_ws, size_t ws_size,
                              hipStream_t stream) {
    const float* x     = (const float*)d_in[0];
    const float* wt    = (const float*)d_in[1];
    const float* gamma = (const float*)d_in[2];
    const float* beta  = (const float*)d_in[3];
    float* out = (float*)d_out;

    char* ws = (char*)d_ws;
    unsigned long long* stats = (unsigned long long*)ws;      // 2048 B (fallback only)
    float2* coef = (float2*)(ws + 2048);                      // 1024 B
    char* wswz = ws + 4096;                                   // 147456 B
    int2* partials = (int2*)(ws + 262144);                    // 2048*128*8 = 2 MB
    char* x8   = ws + 262144 + 2097152;                       // 16*130*17408 = 36208640 B
    const size_t x8_bytes = (size_t)Nn * NROW * ROWP;
    short* conv16 = (short*)(ws + 262144 + 2097152 + x8_bytes);
    const size_t need16 = 262144 + 2097152 + x8_bytes + (size_t)NHW * Cc * 2;

    pack_xw<<<PACKX_BLOCKS + 36, 256, 0, stream>>>(x, wt, x8, wswz);

    if (ws_size >= need16) {
        conv_mfma2<short><<<Nn * Hh, 256, 0, stream>>>(x8, wswz, conv16, partials);
        reduce_coef<<<Cc, 256, 0, stream>>>(partials, gamma, beta, coef);
        apply16<<<Nn * Cc, 256, 0, stream>>>(out, conv16, x, coef, gamma, beta);
    } else {
        hipMemsetAsync(stats, 0, 2048, stream);
        conv_mfma2<float><<<Nn * Hh, 256, 0, stream>>>(x8, wswz, out, partials);
        statsf<<<Nn * Cc, 256, 0, stream>>>(out, stats);
        applyf<<<Nn * Cc, 256, 0, stream>>>(out, x, stats, gamma, beta);
    }
}